// Round 4
// baseline (1038.672 us; speedup 1.0000x reference)
//
#include <hip/hip_runtime.h>
#include <hip/hip_bf16.h>

// GCN 2-layer forward. CSR pull-aggregation, bf16 MFMA for both GEMMs,
// agg1+gemm2 fused (agg1 never materialized), agg2+log_softmax fused.
// N=100000, F_IN=512, HID=128, C=40, E=1.6M (+N self loops)

#define F_IN 512
#define HID  128
#define NC   40

typedef __attribute__((ext_vector_type(8))) short bf16x8;
typedef __attribute__((ext_vector_type(4))) float f32x4v;

__device__ __forceinline__ ushort f2bf(float f) {
    union { float f; unsigned u; } x; x.f = f;
    unsigned r = x.u + 0x7FFFu + ((x.u >> 16) & 1u);   // round-to-nearest-even
    return (ushort)(r >> 16);
}
__device__ __forceinline__ float bf2f(ushort u) {
    return __uint_as_float((unsigned)u << 16);
}

// ---------------- degree count ----------------
__global__ void count_deg(const int* __restrict__ dst, int E, unsigned* __restrict__ cnt) {
    int t = blockIdx.x * blockDim.x + threadIdx.x;
    if (t < E) atomicAdd(&cnt[dst[t]], 1u);
}

__global__ void dis_k(const unsigned* __restrict__ cnt, float* __restrict__ dis, int N) {
    int t = blockIdx.x * blockDim.x + threadIdx.x;
    if (t < N) dis[t] = rsqrtf((float)cnt[t] + 1.0f);  // +1 = self loop
}

// ---------------- prefix sum over deg_total = cnt+1 -> offs (exclusive) -------
__global__ __launch_bounds__(1024) void scan_block(const unsigned* __restrict__ cnt,
                                                   unsigned* __restrict__ offs,
                                                   unsigned* __restrict__ bsums, int N) {
    __shared__ unsigned s[1024];
    int tid = threadIdx.x;
    int i = blockIdx.x * 1024 + tid;
    unsigned v = (i < N) ? cnt[i] + 1u : 0u;
    s[tid] = v;
    __syncthreads();
    #pragma unroll
    for (int d = 1; d < 1024; d <<= 1) {
        unsigned t = (tid >= d) ? s[tid - d] : 0u;
        __syncthreads();
        s[tid] += t;
        __syncthreads();
    }
    if (i < N) offs[i] = s[tid] - v;
    if (tid == 1023) bsums[blockIdx.x] = s[1023];
}

// parallel exclusive scan of block sums (nb <= 1024)
__global__ __launch_bounds__(1024) void scan_bsums(unsigned* __restrict__ bsums, int nb) {
    __shared__ unsigned s[1024];
    int tid = threadIdx.x;
    unsigned v = (tid < nb) ? bsums[tid] : 0u;
    s[tid] = v;
    __syncthreads();
    #pragma unroll
    for (int d = 1; d < 1024; d <<= 1) {
        unsigned t = (tid >= d) ? s[tid - d] : 0u;
        __syncthreads();
        s[tid] += t;
        __syncthreads();
    }
    if (tid < nb) bsums[tid] = s[tid] - v;   // exclusive
}

__global__ __launch_bounds__(1024) void scan_add(unsigned* __restrict__ offs,
                                                 const unsigned* __restrict__ bsums,
                                                 int N, unsigned total) {
    int i = blockIdx.x * 1024 + threadIdx.x;
    if (i < N) offs[i] += bsums[blockIdx.x];
    if (i == 0) offs[N] = total;
}

// ---------------- CSR fill ----------------
__global__ void fill_csr(const int* __restrict__ src, const int* __restrict__ dst,
                         const unsigned* __restrict__ offs, unsigned* __restrict__ cursor,
                         int* __restrict__ col, int E, int N) {
    int t = blockIdx.x * blockDim.x + threadIdx.x;
    if (t >= E + N) return;
    int s, d;
    if (t < E) { s = src[t]; d = dst[t]; } else { s = d = t - E; }
    unsigned pos = offs[d] + atomicAdd(&cursor[d], 1u);
    col[pos] = s;
}

// ---------------- W1 pre-pack: fp32[512][128] -> bf16 fragment layout --------
// Bp layout: [s(16)][kb(4)][n(128)][j(8)], k = s*32 + kb*8 + j
__global__ void w1pack(const float* __restrict__ W1, ushort* __restrict__ Bp) {
    int t = blockIdx.x * 256 + threadIdx.x;   // 0..65535
    int j = t & 7, n = (t >> 3) & 127, kb = (t >> 10) & 3, s = t >> 12;
    int k = s * 32 + kb * 8 + j;
    Bp[t] = f2bf(W1[(size_t)k * HID + n]);
}

// ---------------- W2 pre-pack: fp32[128][40] -> bf16 frag layout, pad n to 48
// Bp layout: [ks(4)][kb(4)][n(48)][j(8)], k = ks*32 + kb*8 + j
__global__ void w2pack(const float* __restrict__ W2, ushort* __restrict__ Bp) {
    int t = blockIdx.x * 256 + threadIdx.x;   // 0..6143
    int j = t & 7;
    int i2 = t >> 3;
    int n = i2 % 48;
    int i3 = i2 / 48;
    int kb = i3 & 3, ks = i3 >> 2;
    int k = ks * 32 + kb * 8 + j;
    float v = (n < NC) ? W2[(size_t)k * NC + n] : 0.f;
    Bp[t] = f2bf(v);
}

// ---------------- GEMM1 MFMA: h1_bf16[N,128] = bf16(x[N,512]) @ W1 -----------
__global__ __launch_bounds__(256) void gemm1_mfma(const float* __restrict__ A,
                                                  const ushort* __restrict__ Bp,
                                                  ushort* __restrict__ C, int N) {
    __shared__ __align__(16) ushort As[128 * 40];
    __shared__ __align__(16) ushort Bs[4096];
    const int tid  = threadIdx.x;
    const int wave = tid >> 6;
    const int lane = tid & 63;
    const int quad = lane >> 4;
    const int mr   = lane & 15;
    const int bm   = blockIdx.x * 128;

    const int r  = tid >> 1;
    const int hh = tid & 1;
    const bool arow_ok = (bm + r) < N;
    const float* arow = A + (size_t)(bm + r) * F_IN + hh * 16;

    f32x4v acc[2][8];
    #pragma unroll
    for (int i = 0; i < 2; i++)
        #pragma unroll
        for (int t = 0; t < 8; t++)
            acc[i][t] = (f32x4v){0.f, 0.f, 0.f, 0.f};

    for (int s = 0; s < 16; s++) {
        {
            const uint4* srcp = (const uint4*)(Bp + (size_t)s * 4096) + tid * 2;
            uint4 v0 = srcp[0], v1 = srcp[1];
            uint4* dstp = (uint4*)Bs + tid * 2;
            dstp[0] = v0; dstp[1] = v1;
        }
        {
            ushort tmp[16];
            if (arow_ok) {
                const float4* ap = (const float4*)(arow + s * 32);
                #pragma unroll
                for (int i = 0; i < 4; i++) {
                    float4 v = ap[i];
                    tmp[i*4+0] = f2bf(v.x); tmp[i*4+1] = f2bf(v.y);
                    tmp[i*4+2] = f2bf(v.z); tmp[i*4+3] = f2bf(v.w);
                }
            } else {
                #pragma unroll
                for (int i = 0; i < 16; i++) tmp[i] = 0;
            }
            uint4* dstp = (uint4*)&As[r * 40 + hh * 16];
            dstp[0] = ((const uint4*)tmp)[0];
            dstp[1] = ((const uint4*)tmp)[1];
        }
        __syncthreads();
        bf16x8 a0 = *(const bf16x8*)&As[(wave * 32 + mr) * 40 + quad * 8];
        bf16x8 a1 = *(const bf16x8*)&As[(wave * 32 + 16 + mr) * 40 + quad * 8];
        #pragma unroll
        for (int t = 0; t < 8; t++) {
            bf16x8 b = *(const bf16x8*)&Bs[quad * 1024 + (t * 16 + mr) * 8];
            acc[0][t] = __builtin_amdgcn_mfma_f32_16x16x32_bf16(a0, b, acc[0][t], 0, 0, 0);
            acc[1][t] = __builtin_amdgcn_mfma_f32_16x16x32_bf16(a1, b, acc[1][t], 0, 0, 0);
        }
        __syncthreads();
    }
    #pragma unroll
    for (int i = 0; i < 2; i++) {
        int row0 = bm + wave * 32 + i * 16 + quad * 4;
        #pragma unroll
        for (int rr = 0; rr < 4; rr++) {
            int row = row0 + rr;
            if (row < N) {
                #pragma unroll
                for (int t = 0; t < 8; t++)
                    C[(size_t)row * HID + t * 16 + mr] = f2bf(acc[i][t][rr]);
            }
        }
    }
}

// ------- fused: agg1 (pull) + bias + relu -> LDS bf16 -> MFMA @ W2 -> h2 bf16
__global__ __launch_bounds__(256) void fused_agg_gemm2(
        const ushort* __restrict__ h,       // h1 bf16 [N][128]
        const int* __restrict__ col,
        const unsigned* __restrict__ offs,
        const float* __restrict__ dis,
        const float* __restrict__ b1,
        const ushort* __restrict__ W2p,     // packed [4][4][48][8]
        ushort* __restrict__ h2,            // bf16 [N][40]
        int N) {
    __shared__ __align__(16) ushort As[128 * 136];   // agg tile, row stride 136
    __shared__ __align__(16) ushort Bs[6144];        // packed W2
    const int tid = threadIdx.x;
    const int bm = blockIdx.x * 128;

    // stage W2p (12 KB)
    {
        const uint4* s4 = (const uint4*)W2p;
        uint4* d4 = (uint4*)Bs;
        #pragma unroll
        for (int i = 0; i < 3; i++) d4[tid + i * 256] = s4[tid + i * 256];
    }

    // phase 1: aggregate 128 nodes, 32 lanes/node, 16 nodes per lane-group
    const int grp = tid >> 5;
    const int l32 = tid & 31;
    float4 bb = *(const float4*)(b1 + l32 * 4);
    for (int ln = grp; ln < 128; ln += 8) {
        int node = bm + ln;
        float4 acc = make_float4(0.f, 0.f, 0.f, 0.f);
        if (node < N) {
            unsigned p0 = offs[node], p1 = offs[node + 1];
            float dd = dis[node];
            for (unsigned p = p0; p < p1; ++p) {
                int s = col[p];
                float nrm = dis[s] * dd;
                ushort4 v = *(const ushort4*)(h + (size_t)s * HID + l32 * 4);
                acc.x += bf2f(v.x) * nrm; acc.y += bf2f(v.y) * nrm;
                acc.z += bf2f(v.z) * nrm; acc.w += bf2f(v.w) * nrm;
            }
            acc.x = fmaxf(acc.x + bb.x, 0.f);
            acc.y = fmaxf(acc.y + bb.y, 0.f);
            acc.z = fmaxf(acc.z + bb.z, 0.f);
            acc.w = fmaxf(acc.w + bb.w, 0.f);
        }
        ushort4 o;
        o.x = f2bf(acc.x); o.y = f2bf(acc.y); o.z = f2bf(acc.z); o.w = f2bf(acc.w);
        *(ushort4*)&As[ln * 136 + l32 * 4] = o;
    }
    __syncthreads();

    // phase 2: [128x40] = As[128x128] @ W2[128x40(pad48)], 16x16x32 MFMA
    const int wave = tid >> 6;
    const int lane = tid & 63;
    const int quad = lane >> 4;
    const int mr   = lane & 15;
    f32x4v acc[2][3];
    #pragma unroll
    for (int i = 0; i < 2; i++)
        #pragma unroll
        for (int t = 0; t < 3; t++)
            acc[i][t] = (f32x4v){0.f, 0.f, 0.f, 0.f};
    #pragma unroll
    for (int ks = 0; ks < 4; ks++) {
        bf16x8 a0 = *(const bf16x8*)&As[(wave * 32 + mr) * 136 + ks * 32 + quad * 8];
        bf16x8 a1 = *(const bf16x8*)&As[(wave * 32 + 16 + mr) * 136 + ks * 32 + quad * 8];
        #pragma unroll
        for (int t = 0; t < 3; t++) {
            bf16x8 b = *(const bf16x8*)&Bs[((ks * 4 + quad) * 48 + t * 16 + mr) * 8];
            acc[0][t] = __builtin_amdgcn_mfma_f32_16x16x32_bf16(a0, b, acc[0][t], 0, 0, 0);
            acc[1][t] = __builtin_amdgcn_mfma_f32_16x16x32_bf16(a1, b, acc[1][t], 0, 0, 0);
        }
    }
    #pragma unroll
    for (int i = 0; i < 2; i++) {
        #pragma unroll
        for (int t = 0; t < 3; t++) {
            int c = t * 16 + mr;
            if (c < NC) {
                #pragma unroll
                for (int rr = 0; rr < 4; rr++) {
                    int node = bm + wave * 32 + i * 16 + quad * 4 + rr;
                    if (node < N)
                        h2[(size_t)node * NC + c] = f2bf(acc[i][t][rr]);
                }
            }
        }
    }
}

// ------- fused: agg2 (pull, bf16 h2) + b2 + log_softmax -> out fp32 ----------
__global__ __launch_bounds__(256) void agg2_ls(const ushort* __restrict__ h2,
                                               const int* __restrict__ col,
                                               const unsigned* __restrict__ offs,
                                               const float* __restrict__ dis,
                                               const float* __restrict__ b2,
                                               float* __restrict__ out, int N) {
    int node = blockIdx.x * 32 + (threadIdx.x >> 3);
    if (node >= N) return;
    int lane = threadIdx.x & 7;
    unsigned p0 = offs[node], p1 = offs[node + 1];
    float dd = dis[node];
    float4 a  = make_float4(0.f, 0.f, 0.f, 0.f);   // cols lane*4 .. +3
    float4 a2 = make_float4(0.f, 0.f, 0.f, 0.f);   // lanes 0,1: cols 32+lane*4 ..
    for (unsigned p = p0; p < p1; ++p) {
        int s = col[p];
        float nrm = dis[s] * dd;
        const ushort* hp = h2 + (size_t)s * NC;
        ushort4 v = *(const ushort4*)(hp + lane * 4);
        a.x += bf2f(v.x) * nrm; a.y += bf2f(v.y) * nrm;
        a.z += bf2f(v.z) * nrm; a.w += bf2f(v.w) * nrm;
        if (lane < 2) {
            ushort4 w = *(const ushort4*)(hp + 32 + lane * 4);
            a2.x += bf2f(w.x) * nrm; a2.y += bf2f(w.y) * nrm;
            a2.z += bf2f(w.z) * nrm; a2.w += bf2f(w.w) * nrm;
        }
    }
    float4 bb = *(const float4*)(b2 + lane * 4);
    a.x += bb.x; a.y += bb.y; a.z += bb.z; a.w += bb.w;
    if (lane < 2) {
        float4 b2v = *(const float4*)(b2 + 32 + lane * 4);
        a2.x += b2v.x; a2.y += b2v.y; a2.z += b2v.z; a2.w += b2v.w;
    }
    // max over 40
    float m = fmaxf(fmaxf(a.x, a.y), fmaxf(a.z, a.w));
    if (lane < 2) m = fmaxf(m, fmaxf(fmaxf(a2.x, a2.y), fmaxf(a2.z, a2.w)));
    #pragma unroll
    for (int d = 1; d < 8; d <<= 1) m = fmaxf(m, __shfl_xor(m, d, 8));
    // sum exp
    float s = __expf(a.x - m) + __expf(a.y - m) + __expf(a.z - m) + __expf(a.w - m);
    if (lane < 2) s += __expf(a2.x - m) + __expf(a2.y - m) + __expf(a2.z - m) + __expf(a2.w - m);
    #pragma unroll
    for (int d = 1; d < 8; d <<= 1) s += __shfl_xor(s, d, 8);
    float lse = m + __logf(s);
    float* op = out + (size_t)node * NC;
    *(float4*)(op + lane * 4) = make_float4(a.x - lse, a.y - lse, a.z - lse, a.w - lse);
    if (lane < 2)
        *(float4*)(op + 32 + lane * 4) = make_float4(a2.x - lse, a2.y - lse, a2.z - lse, a2.w - lse);
}

extern "C" void kernel_launch(void* const* d_in, const int* in_sizes, int n_in,
                              void* d_out, int out_size, void* d_ws, size_t ws_size,
                              hipStream_t stream) {
    const float* x  = (const float*)d_in[0];
    const int*   ei = (const int*)d_in[1];
    const float* W1 = (const float*)d_in[2];
    const float* b1 = (const float*)d_in[3];
    const float* W2 = (const float*)d_in[4];
    const float* b2 = (const float*)d_in[5];
    float* out = (float*)d_out;

    const int N = in_sizes[0] / F_IN;     // 100000
    const int E = in_sizes[1] / 2;        // 1600000
    const int EN = E + N;
    const int* src = ei;
    const int* dst = ei + E;

    // ---- workspace layout ----
    char* ws = (char*)d_ws;
    size_t o = 0;
    unsigned* cnt  = (unsigned*)(ws + o); o += (size_t)N * 4;        // reused as cursor
    float*    dis  = (float*)   (ws + o); o += (size_t)N * 4;
    unsigned* offs = (unsigned*)(ws + o); o += (size_t)(N + 4) * 4;
    unsigned* bsums= (unsigned*)(ws + o); o += 4096;
    int*      col  = (int*)     (ws + o); o += (size_t)EN * 4;
    o = (o + 15) & ~(size_t)15;
    ushort*   W1p  = (ushort*)  (ws + o); o += (size_t)F_IN * HID * 2;   // 128 KB
    o = (o + 15) & ~(size_t)15;
    ushort*   W2p  = (ushort*)  (ws + o); o += 6144 * 2;                 // 12 KB
    o = (o + 15) & ~(size_t)15;
    ushort*   h1   = (ushort*)  (ws + o); o += (size_t)N * HID * 2;      // 25.6 MB
    o = (o + 15) & ~(size_t)15;
    ushort*   h2   = (ushort*)  (ws + o); o += (size_t)N * NC * 2;       // 8 MB

    const int nb = (N + 1023) / 1024;

    // degree + norm
    hipMemsetAsync(cnt, 0, (size_t)N * 4, stream);
    count_deg<<<(E + 255) / 256, 256, 0, stream>>>(dst, E, cnt);
    dis_k<<<(N + 255) / 256, 256, 0, stream>>>(cnt, dis, N);

    // prefix sum -> offs
    scan_block<<<nb, 1024, 0, stream>>>(cnt, offs, bsums, N);
    scan_bsums<<<1, 1024, 0, stream>>>(bsums, nb);
    scan_add<<<nb, 1024, 0, stream>>>(offs, bsums, N, (unsigned)EN);

    // fill CSR (cnt reused as cursor)
    hipMemsetAsync(cnt, 0, (size_t)N * 4, stream);
    fill_csr<<<(EN + 255) / 256, 256, 0, stream>>>(src, dst, offs, cnt, col, E, N);

    // weight packs
    w1pack<<<(F_IN * HID) / 256, 256, 0, stream>>>(W1, W1p);
    w2pack<<<6144 / 256, 256, 0, stream>>>(W2, W2p);

    // layer 1 GEMM
    gemm1_mfma<<<(N + 127) / 128, 256, 0, stream>>>(x, W1p, h1, N);

    // agg1 + bias + relu + GEMM2 fused
    fused_agg_gemm2<<<(N + 127) / 128, 256, 0, stream>>>(h1, col, offs, dis, b1, W2p, h2, N);

    // agg2 + b2 + log_softmax fused
    agg2_ls<<<(N + 31) / 32, 256, 0, stream>>>(h2, col, offs, dis, b2, out, N);
}

// Round 5
// 618.569 us; speedup vs baseline: 1.6792x; 1.6792x over previous
//
#include <hip/hip_runtime.h>
#include <hip/hip_bf16.h>

// GCN 2-layer forward. CSR pull-aggregation (one node per lane-group — TLP is
// king for the latency-bound gather; round-4 fusion proved serializing nodes
// costs 3.4x). dis pre-scaled into h1/h2 rows so agg loops are pure gathers.
// N=100000, F_IN=512, HID=128, C=40, E=1.6M (+N self loops)

#define F_IN 512
#define HID  128
#define NC   40

typedef __attribute__((ext_vector_type(8))) short bf16x8;
typedef __attribute__((ext_vector_type(4))) float f32x4v;

__device__ __forceinline__ ushort f2bf(float f) {
    union { float f; unsigned u; } x; x.f = f;
    unsigned r = x.u + 0x7FFFu + ((x.u >> 16) & 1u);   // round-to-nearest-even
    return (ushort)(r >> 16);
}
__device__ __forceinline__ float bf2f(ushort u) {
    return __uint_as_float((unsigned)u << 16);
}

// ---------------- degree count ----------------
__global__ void count_deg(const int* __restrict__ dst, int E, unsigned* __restrict__ cnt) {
    int t = blockIdx.x * blockDim.x + threadIdx.x;
    if (t < E) atomicAdd(&cnt[dst[t]], 1u);
}

__global__ void dis_k(const unsigned* __restrict__ cnt, float* __restrict__ dis, int N) {
    int t = blockIdx.x * blockDim.x + threadIdx.x;
    if (t < N) dis[t] = rsqrtf((float)cnt[t] + 1.0f);  // +1 = self loop
}

// ---------------- prefix sum over deg_total = cnt+1 -> offs (exclusive) -------
__global__ __launch_bounds__(1024) void scan_block(const unsigned* __restrict__ cnt,
                                                   unsigned* __restrict__ offs,
                                                   unsigned* __restrict__ bsums, int N) {
    __shared__ unsigned s[1024];
    int tid = threadIdx.x;
    int i = blockIdx.x * 1024 + tid;
    unsigned v = (i < N) ? cnt[i] + 1u : 0u;
    s[tid] = v;
    __syncthreads();
    #pragma unroll
    for (int d = 1; d < 1024; d <<= 1) {
        unsigned t = (tid >= d) ? s[tid - d] : 0u;
        __syncthreads();
        s[tid] += t;
        __syncthreads();
    }
    if (i < N) offs[i] = s[tid] - v;
    if (tid == 1023) bsums[blockIdx.x] = s[1023];
}

__global__ __launch_bounds__(1024) void scan_bsums(unsigned* __restrict__ bsums, int nb) {
    __shared__ unsigned s[1024];
    int tid = threadIdx.x;
    unsigned v = (tid < nb) ? bsums[tid] : 0u;
    s[tid] = v;
    __syncthreads();
    #pragma unroll
    for (int d = 1; d < 1024; d <<= 1) {
        unsigned t = (tid >= d) ? s[tid - d] : 0u;
        __syncthreads();
        s[tid] += t;
        __syncthreads();
    }
    if (tid < nb) bsums[tid] = s[tid] - v;   // exclusive
}

__global__ __launch_bounds__(1024) void scan_add(unsigned* __restrict__ offs,
                                                 const unsigned* __restrict__ bsums,
                                                 int N, unsigned total) {
    int i = blockIdx.x * 1024 + threadIdx.x;
    if (i < N) offs[i] += bsums[blockIdx.x];
    if (i == 0) offs[N] = total;
}

// ---------------- CSR fill ----------------
__global__ void fill_csr(const int* __restrict__ src, const int* __restrict__ dst,
                         const unsigned* __restrict__ offs, unsigned* __restrict__ cursor,
                         int* __restrict__ col, int E, int N) {
    int t = blockIdx.x * blockDim.x + threadIdx.x;
    if (t >= E + N) return;
    int s, d;
    if (t < E) { s = src[t]; d = dst[t]; } else { s = d = t - E; }
    unsigned pos = offs[d] + atomicAdd(&cursor[d], 1u);
    col[pos] = s;
}

// ---------------- W1 pre-pack: fp32[512][128] -> bf16 fragment layout --------
// Bp layout: [s(16)][kb(4)][n(128)][j(8)], k = s*32 + kb*8 + j
__global__ void w1pack(const float* __restrict__ W1, ushort* __restrict__ Bp) {
    int t = blockIdx.x * 256 + threadIdx.x;   // 0..65535
    int j = t & 7, n = (t >> 3) & 127, kb = (t >> 10) & 3, s = t >> 12;
    int k = s * 32 + kb * 8 + j;
    Bp[t] = f2bf(W1[(size_t)k * HID + n]);
}

// ---------------- W2 pre-pack: fp32[128][40] -> bf16 frag layout, pad n to 48
// Bp layout: [ks(4)][kb(4)][n(48)][j(8)], k = ks*32 + kb*8 + j
__global__ void w2pack(const float* __restrict__ W2, ushort* __restrict__ Bp) {
    int t = blockIdx.x * 256 + threadIdx.x;   // 0..6143
    int j = t & 7;
    int i2 = t >> 3;
    int n = i2 % 48;
    int i3 = i2 / 48;
    int kb = i3 & 3, ks = i3 >> 2;
    int k = ks * 32 + kb * 8 + j;
    float v = (n < NC) ? W2[(size_t)k * NC + n] : 0.f;
    Bp[t] = f2bf(v);
}

// ------- GEMM1 MFMA: h1s[N,128] = (bf16(x) @ W1) * dis[row]  (bf16 out) -----
__global__ __launch_bounds__(256) void gemm1_mfma(const float* __restrict__ A,
                                                  const ushort* __restrict__ Bp,
                                                  const float* __restrict__ dis,
                                                  ushort* __restrict__ C, int N) {
    __shared__ __align__(16) ushort As[128 * 40];
    __shared__ __align__(16) ushort Bs[4096];
    const int tid  = threadIdx.x;
    const int wave = tid >> 6;
    const int lane = tid & 63;
    const int quad = lane >> 4;
    const int mr   = lane & 15;
    const int bm   = blockIdx.x * 128;

    const int r  = tid >> 1;
    const int hh = tid & 1;
    const bool arow_ok = (bm + r) < N;
    const float* arow = A + (size_t)(bm + r) * F_IN + hh * 16;

    f32x4v acc[2][8];
    #pragma unroll
    for (int i = 0; i < 2; i++)
        #pragma unroll
        for (int t = 0; t < 8; t++)
            acc[i][t] = (f32x4v){0.f, 0.f, 0.f, 0.f};

    for (int s = 0; s < 16; s++) {
        {
            const uint4* srcp = (const uint4*)(Bp + (size_t)s * 4096) + tid * 2;
            uint4 v0 = srcp[0], v1 = srcp[1];
            uint4* dstp = (uint4*)Bs + tid * 2;
            dstp[0] = v0; dstp[1] = v1;
        }
        {
            ushort tmp[16];
            if (arow_ok) {
                const float4* ap = (const float4*)(arow + s * 32);
                #pragma unroll
                for (int i = 0; i < 4; i++) {
                    float4 v = ap[i];
                    tmp[i*4+0] = f2bf(v.x); tmp[i*4+1] = f2bf(v.y);
                    tmp[i*4+2] = f2bf(v.z); tmp[i*4+3] = f2bf(v.w);
                }
            } else {
                #pragma unroll
                for (int i = 0; i < 16; i++) tmp[i] = 0;
            }
            uint4* dstp = (uint4*)&As[r * 40 + hh * 16];
            dstp[0] = ((const uint4*)tmp)[0];
            dstp[1] = ((const uint4*)tmp)[1];
        }
        __syncthreads();
        bf16x8 a0 = *(const bf16x8*)&As[(wave * 32 + mr) * 40 + quad * 8];
        bf16x8 a1 = *(const bf16x8*)&As[(wave * 32 + 16 + mr) * 40 + quad * 8];
        #pragma unroll
        for (int t = 0; t < 8; t++) {
            bf16x8 b = *(const bf16x8*)&Bs[quad * 1024 + (t * 16 + mr) * 8];
            acc[0][t] = __builtin_amdgcn_mfma_f32_16x16x32_bf16(a0, b, acc[0][t], 0, 0, 0);
            acc[1][t] = __builtin_amdgcn_mfma_f32_16x16x32_bf16(a1, b, acc[1][t], 0, 0, 0);
        }
        __syncthreads();
    }
    #pragma unroll
    for (int i = 0; i < 2; i++) {
        int row0 = bm + wave * 32 + i * 16 + quad * 4;
        #pragma unroll
        for (int rr = 0; rr < 4; rr++) {
            int row = row0 + rr;
            if (row < N) {
                float ds = dis[row];
                #pragma unroll
                for (int t = 0; t < 8; t++)
                    C[(size_t)row * HID + t * 16 + mr] = f2bf(acc[i][t][rr] * ds);
            }
        }
    }
}

// ------- agg1: one node per 32-lane group, pure gather-accumulate, x4 unroll -
// out[node] = dis[node] * sum_{s in N(node)} h1s[s]   (h1s already dis-scaled)
__global__ __launch_bounds__(256) void agg1_k(const ushort* __restrict__ h,
                                              const int* __restrict__ col,
                                              const unsigned* __restrict__ offs,
                                              const float* __restrict__ dis,
                                              ushort* __restrict__ out, int N) {
    int node = blockIdx.x * 8 + (threadIdx.x >> 5);
    if (node >= N) return;
    int lane = threadIdx.x & 31;
    unsigned p0 = offs[node], p1 = offs[node + 1];
    float4 a0 = make_float4(0.f, 0.f, 0.f, 0.f);
    float4 a1 = make_float4(0.f, 0.f, 0.f, 0.f);
    float4 a2 = make_float4(0.f, 0.f, 0.f, 0.f);
    float4 a3 = make_float4(0.f, 0.f, 0.f, 0.f);
    unsigned p = p0;
    for (; p + 4 <= p1; p += 4) {
        int s0 = col[p], s1 = col[p+1], s2 = col[p+2], s3 = col[p+3];
        ushort4 v0 = *(const ushort4*)(h + (size_t)s0 * HID + lane * 4);
        ushort4 v1 = *(const ushort4*)(h + (size_t)s1 * HID + lane * 4);
        ushort4 v2 = *(const ushort4*)(h + (size_t)s2 * HID + lane * 4);
        ushort4 v3 = *(const ushort4*)(h + (size_t)s3 * HID + lane * 4);
        a0.x += bf2f(v0.x); a0.y += bf2f(v0.y); a0.z += bf2f(v0.z); a0.w += bf2f(v0.w);
        a1.x += bf2f(v1.x); a1.y += bf2f(v1.y); a1.z += bf2f(v1.z); a1.w += bf2f(v1.w);
        a2.x += bf2f(v2.x); a2.y += bf2f(v2.y); a2.z += bf2f(v2.z); a2.w += bf2f(v2.w);
        a3.x += bf2f(v3.x); a3.y += bf2f(v3.y); a3.z += bf2f(v3.z); a3.w += bf2f(v3.w);
    }
    for (; p < p1; ++p) {
        int s = col[p];
        ushort4 v = *(const ushort4*)(h + (size_t)s * HID + lane * 4);
        a0.x += bf2f(v.x); a0.y += bf2f(v.y); a0.z += bf2f(v.z); a0.w += bf2f(v.w);
    }
    float dd = dis[node];
    float4 a;
    a.x = ((a0.x + a1.x) + (a2.x + a3.x)) * dd;
    a.y = ((a0.y + a1.y) + (a2.y + a3.y)) * dd;
    a.z = ((a0.z + a1.z) + (a2.z + a3.z)) * dd;
    a.w = ((a0.w + a1.w) + (a2.w + a3.w)) * dd;
    ushort4 o;
    o.x = f2bf(a.x); o.y = f2bf(a.y); o.z = f2bf(a.z); o.w = f2bf(a.w);
    *(ushort4*)(out + (size_t)node * HID + lane * 4) = o;
}

// ------- GEMM2 MFMA: h2s[N,40] = (relu(agg1 + b1) @ W2) * dis[row] (bf16) ---
__global__ __launch_bounds__(256) void gemm2_mfma(const ushort* __restrict__ A,
                                                  const float* __restrict__ b1,
                                                  const ushort* __restrict__ W2p,
                                                  const float* __restrict__ dis,
                                                  ushort* __restrict__ h2, int N) {
    __shared__ __align__(16) ushort As[128 * 136];
    __shared__ __align__(16) ushort Bs[6144];
    const int tid = threadIdx.x;
    const int bm = blockIdx.x * 128;

    // stage W2p (12 KB)
    {
        const uint4* s4 = (const uint4*)W2p;
        uint4* d4 = (uint4*)Bs;
        #pragma unroll
        for (int i = 0; i < 3; i++) d4[tid + i * 256] = s4[tid + i * 256];
    }
    // stage A half-row per thread: bias + relu, bf16 -> bf16
    {
        const int r  = tid >> 1;
        const int hh = tid & 1;
        const int row = bm + r;
        const float* brow = b1 + hh * 64;
        if (row < N) {
            const ushort* arow = A + (size_t)row * HID + hh * 64;
            #pragma unroll
            for (int i = 0; i < 8; i++) {
                uint4 raw = *(const uint4*)(arow + i * 8);
                const ushort* u = (const ushort*)&raw;
                ushort tmp[8];
                #pragma unroll
                for (int j = 0; j < 8; j++)
                    tmp[j] = f2bf(fmaxf(bf2f(u[j]) + brow[i * 8 + j], 0.f));
                *(uint4*)&As[r * 136 + hh * 64 + i * 8] = *(const uint4*)tmp;
            }
        } else {
            #pragma unroll
            for (int i = 0; i < 8; i++) {
                uint4 z = {0, 0, 0, 0};
                *(uint4*)&As[r * 136 + hh * 64 + i * 8] = z;
            }
        }
    }
    __syncthreads();

    const int wave = tid >> 6;
    const int lane = tid & 63;
    const int quad = lane >> 4;
    const int mr   = lane & 15;
    f32x4v acc[2][3];
    #pragma unroll
    for (int i = 0; i < 2; i++)
        #pragma unroll
        for (int t = 0; t < 3; t++)
            acc[i][t] = (f32x4v){0.f, 0.f, 0.f, 0.f};
    #pragma unroll
    for (int ks = 0; ks < 4; ks++) {
        bf16x8 a0 = *(const bf16x8*)&As[(wave * 32 + mr) * 136 + ks * 32 + quad * 8];
        bf16x8 a1 = *(const bf16x8*)&As[(wave * 32 + 16 + mr) * 136 + ks * 32 + quad * 8];
        #pragma unroll
        for (int t = 0; t < 3; t++) {
            bf16x8 b = *(const bf16x8*)&Bs[((ks * 4 + quad) * 48 + t * 16 + mr) * 8];
            acc[0][t] = __builtin_amdgcn_mfma_f32_16x16x32_bf16(a0, b, acc[0][t], 0, 0, 0);
            acc[1][t] = __builtin_amdgcn_mfma_f32_16x16x32_bf16(a1, b, acc[1][t], 0, 0, 0);
        }
    }
    #pragma unroll
    for (int i = 0; i < 2; i++) {
        #pragma unroll
        for (int rr = 0; rr < 4; rr++) {
            int node = bm + wave * 32 + i * 16 + quad * 4 + rr;
            if (node < N) {
                float ds = dis[node];
                #pragma unroll
                for (int t = 0; t < 3; t++) {
                    int c = t * 16 + mr;
                    if (c < NC)
                        h2[(size_t)node * NC + c] = f2bf(acc[i][t][rr] * ds);
                }
            }
        }
    }
}

// ------- agg2 + b2 + log_softmax: one node per 8-lane group ------------------
// logits = dis[node] * sum h2s[s] + b2
__global__ __launch_bounds__(256) void agg2_ls(const ushort* __restrict__ h2,
                                               const int* __restrict__ col,
                                               const unsigned* __restrict__ offs,
                                               const float* __restrict__ dis,
                                               const float* __restrict__ b2,
                                               float* __restrict__ out, int N) {
    int node = blockIdx.x * 32 + (threadIdx.x >> 3);
    if (node >= N) return;
    int lane = threadIdx.x & 7;
    unsigned p0 = offs[node], p1 = offs[node + 1];
    float4 a  = make_float4(0.f, 0.f, 0.f, 0.f);
    float4 a2 = make_float4(0.f, 0.f, 0.f, 0.f);
    float4 c  = make_float4(0.f, 0.f, 0.f, 0.f);
    float4 c2 = make_float4(0.f, 0.f, 0.f, 0.f);
    unsigned p = p0;
    for (; p + 2 <= p1; p += 2) {
        int s0 = col[p], s1 = col[p + 1];
        const ushort* hp0 = h2 + (size_t)s0 * NC;
        const ushort* hp1 = h2 + (size_t)s1 * NC;
        ushort4 v0 = *(const ushort4*)(hp0 + lane * 4);
        ushort4 v1 = *(const ushort4*)(hp1 + lane * 4);
        a.x += bf2f(v0.x); a.y += bf2f(v0.y); a.z += bf2f(v0.z); a.w += bf2f(v0.w);
        c.x += bf2f(v1.x); c.y += bf2f(v1.y); c.z += bf2f(v1.z); c.w += bf2f(v1.w);
        if (lane < 2) {
            ushort4 w0 = *(const ushort4*)(hp0 + 32 + lane * 4);
            ushort4 w1 = *(const ushort4*)(hp1 + 32 + lane * 4);
            a2.x += bf2f(w0.x); a2.y += bf2f(w0.y); a2.z += bf2f(w0.z); a2.w += bf2f(w0.w);
            c2.x += bf2f(w1.x); c2.y += bf2f(w1.y); c2.z += bf2f(w1.z); c2.w += bf2f(w1.w);
        }
    }
    for (; p < p1; ++p) {
        int s = col[p];
        const ushort* hp = h2 + (size_t)s * NC;
        ushort4 v = *(const ushort4*)(hp + lane * 4);
        a.x += bf2f(v.x); a.y += bf2f(v.y); a.z += bf2f(v.z); a.w += bf2f(v.w);
        if (lane < 2) {
            ushort4 w = *(const ushort4*)(hp + 32 + lane * 4);
            a2.x += bf2f(w.x); a2.y += bf2f(w.y); a2.z += bf2f(w.z); a2.w += bf2f(w.w);
        }
    }
    float dd = dis[node];
    float4 bb = *(const float4*)(b2 + lane * 4);
    a.x = (a.x + c.x) * dd + bb.x; a.y = (a.y + c.y) * dd + bb.y;
    a.z = (a.z + c.z) * dd + bb.z; a.w = (a.w + c.w) * dd + bb.w;
    if (lane < 2) {
        float4 b2v = *(const float4*)(b2 + 32 + lane * 4);
        a2.x = (a2.x + c2.x) * dd + b2v.x; a2.y = (a2.y + c2.y) * dd + b2v.y;
        a2.z = (a2.z + c2.z) * dd + b2v.z; a2.w = (a2.w + c2.w) * dd + b2v.w;
    }
    float m = fmaxf(fmaxf(a.x, a.y), fmaxf(a.z, a.w));
    if (lane < 2) m = fmaxf(m, fmaxf(fmaxf(a2.x, a2.y), fmaxf(a2.z, a2.w)));
    #pragma unroll
    for (int d = 1; d < 8; d <<= 1) m = fmaxf(m, __shfl_xor(m, d, 8));
    float s = __expf(a.x - m) + __expf(a.y - m) + __expf(a.z - m) + __expf(a.w - m);
    if (lane < 2) s += __expf(a2.x - m) + __expf(a2.y - m) + __expf(a2.z - m) + __expf(a2.w - m);
    #pragma unroll
    for (int d = 1; d < 8; d <<= 1) s += __shfl_xor(s, d, 8);
    float lse = m + __logf(s);
    float* op = out + (size_t)node * NC;
    *(float4*)(op + lane * 4) = make_float4(a.x - lse, a.y - lse, a.z - lse, a.w - lse);
    if (lane < 2)
        *(float4*)(op + 32 + lane * 4) = make_float4(a2.x - lse, a2.y - lse, a2.z - lse, a2.w - lse);
}

extern "C" void kernel_launch(void* const* d_in, const int* in_sizes, int n_in,
                              void* d_out, int out_size, void* d_ws, size_t ws_size,
                              hipStream_t stream) {
    const float* x  = (const float*)d_in[0];
    const int*   ei = (const int*)d_in[1];
    const float* W1 = (const float*)d_in[2];
    const float* b1 = (const float*)d_in[3];
    const float* W2 = (const float*)d_in[4];
    const float* b2 = (const float*)d_in[5];
    float* out = (float*)d_out;

    const int N = in_sizes[0] / F_IN;     // 100000
    const int E = in_sizes[1] / 2;        // 1600000
    const int EN = E + N;
    const int* src = ei;
    const int* dst = ei + E;

    // ---- workspace layout ----
    char* ws = (char*)d_ws;
    size_t o = 0;
    unsigned* cnt  = (unsigned*)(ws + o); o += (size_t)N * 4;        // reused as cursor
    float*    dis  = (float*)   (ws + o); o += (size_t)N * 4;
    unsigned* offs = (unsigned*)(ws + o); o += (size_t)(N + 4) * 4;
    unsigned* bsums= (unsigned*)(ws + o); o += 4096;
    int*      col  = (int*)     (ws + o); o += (size_t)EN * 4;
    o = (o + 15) & ~(size_t)15;
    ushort*   W1p  = (ushort*)  (ws + o); o += (size_t)F_IN * HID * 2;   // 128 KB
    o = (o + 15) & ~(size_t)15;
    ushort*   W2p  = (ushort*)  (ws + o); o += 6144 * 2;                 // 12 KB
    o = (o + 15) & ~(size_t)15;
    ushort*   h1   = (ushort*)  (ws + o); o += (size_t)N * HID * 2;      // 25.6 MB
    o = (o + 15) & ~(size_t)15;
    ushort*   ag1  = (ushort*)  (ws + o); o += (size_t)N * HID * 2;      // 25.6 MB
    o = (o + 15) & ~(size_t)15;
    ushort*   h2   = (ushort*)  (ws + o); o += (size_t)N * NC * 2;       // 8 MB

    const int nb = (N + 1023) / 1024;

    // degree + norm
    hipMemsetAsync(cnt, 0, (size_t)N * 4, stream);
    count_deg<<<(E + 255) / 256, 256, 0, stream>>>(dst, E, cnt);
    dis_k<<<(N + 255) / 256, 256, 0, stream>>>(cnt, dis, N);

    // prefix sum -> offs
    scan_block<<<nb, 1024, 0, stream>>>(cnt, offs, bsums, N);
    scan_bsums<<<1, 1024, 0, stream>>>(bsums, nb);
    scan_add<<<nb, 1024, 0, stream>>>(offs, bsums, N, (unsigned)EN);

    // fill CSR (cnt reused as cursor)
    hipMemsetAsync(cnt, 0, (size_t)N * 4, stream);
    fill_csr<<<(EN + 255) / 256, 256, 0, stream>>>(src, dst, offs, cnt, col, E, N);

    // weight packs
    w1pack<<<(F_IN * HID) / 256, 256, 0, stream>>>(W1, W1p);
    w2pack<<<6144 / 256, 256, 0, stream>>>(W2, W2p);

    // layer 1: GEMM (dis-prescaled bf16 out) -> pull aggregation
    gemm1_mfma<<<(N + 127) / 128, 256, 0, stream>>>(x, W1p, dis, h1, N);
    agg1_k<<<(N + 7) / 8, 256, 0, stream>>>(h1, col, offs, dis, ag1, N);

    // layer 2: GEMM (bias+relu in, dis-prescaled bf16 out) -> agg + log_softmax
    gemm2_mfma<<<(N + 127) / 128, 256, 0, stream>>>(ag1, b1, W2p, dis, h2, N);
    agg2_ls<<<(N + 31) / 32, 256, 0, stream>>>(h2, col, offs, dis, b2, out, N);
}